// Round 5
// baseline (357.842 us; speedup 1.0000x reference)
//
#include <hip/hip_runtime.h>
#include <cstdint>
#include <cstddef>

#define B_  4
#define S_  2048
#define D_  1024
#define H_  16
#define HD_ 64
#define M_  (B_ * S_)   // 8192 rows

#define CHUNKS_ 64      // parallel chunks per (b,h) sequence
#define CL_     32      // chunk length; CHUNKS_*CL_ == S_

typedef __bf16 bf16_t;
typedef bf16_t bf16x8 __attribute__((ext_vector_type(8)));
typedef float  floatx4 __attribute__((ext_vector_type(4)));

// ---------------------------------------------------------------------------
// async 16B global -> LDS copy (gfx950). LDS dest is wave-uniform base +
// lane*16 (m104/m108); all uses below pass lds = base + lane*16 exactly.
// ---------------------------------------------------------------------------
__device__ __forceinline__ void async_copy16(const void* gmem, void* lds) {
  __builtin_amdgcn_global_load_lds(
      (__attribute__((address_space(1))) void*)const_cast<void*>(gmem),
      (__attribute__((address_space(3))) void*)lds,
      16, 0, 0);
}

// ---------------------------------------------------------------------------
// Fused prologue: weight fp32->bf16 cast (4M elems) + token-shift mix (8M).
// Grid-region split saves a launch (r4: ~8 us gap per dispatch).
// ---------------------------------------------------------------------------
__global__ void pre_kernel(const float* __restrict__ w0, const float* __restrict__ w1,
                           const float* __restrict__ w2, const float* __restrict__ w3,
                           bf16_t* __restrict__ wout,
                           const float* __restrict__ x,
                           const float* __restrict__ tmr, const float* __restrict__ tmk,
                           const float* __restrict__ tmv,
                           bf16_t* __restrict__ xr, bf16_t* __restrict__ xk,
                           bf16_t* __restrict__ xv) {
  const int ONE_M = 1 << 20;
  int gid = blockIdx.x * blockDim.x + threadIdx.x;
  if (gid < 4 * ONE_M) {
    const float* src = (gid < ONE_M) ? w0 : (gid < 2 * ONE_M) ? w1 : (gid < 3 * ONE_M) ? w2 : w3;
    wout[gid] = (bf16_t)src[gid & (ONE_M - 1)];
  } else {
    int idx = gid - 4 * ONE_M;                 // 0 .. 8M-1
    int d = idx & (D_ - 1);
    int t = (idx / D_) & (S_ - 1);
    float xc = x[idx];
    float xp = (t == 0) ? 0.0f : x[idx - D_];
    float mr = tmr[d], mk = tmk[d], mv = tmv[d];
    xr[idx] = (bf16_t)(xc * mr + xp * (1.0f - mr));
    xk[idx] = (bf16_t)(xc * mk + xp * (1.0f - mk));
    xv[idx] = (bf16_t)(xc * mv + xp * (1.0f - mv));
  }
}

// ---------------------------------------------------------------------------
// Fused 3-projection GEMM: one dispatch computes r=xr@Wr^T, k=xk@Wk^T,
// v=xv@Wv^T. blockIdx.x in [0,24): proj = x>>3, n-block = x&7. m97 tile.
// ---------------------------------------------------------------------------
__global__ __launch_bounds__(256)
void gemm3(const bf16_t* __restrict__ xr, const bf16_t* __restrict__ xk,
           const bf16_t* __restrict__ xv, const bf16_t* __restrict__ Wall,
           float* __restrict__ rbuf, float* __restrict__ kbuf, float* __restrict__ vbuf) {
  constexpr int BM = 128, BN = 128, BK = 32, K = D_, N = D_;
  __shared__ __align__(16) bf16_t As[BM][BK];
  __shared__ __align__(16) bf16_t Bs[BN][BK];

  const int proj = blockIdx.x >> 3;
  const bf16_t* A  = (proj == 0) ? xr : (proj == 1) ? xk : xv;
  const bf16_t* Bw = Wall + (size_t)proj * (1 << 20);
  float* C         = (proj == 0) ? rbuf : (proj == 1) ? kbuf : vbuf;

  const int tid  = threadIdx.x;
  const int lane = tid & 63;
  const int wave = tid >> 6;
  const int wm   = wave >> 1;
  const int wn   = wave & 1;
  const int l15  = lane & 15;
  const int quad = lane >> 4;

  const int n0 = (blockIdx.x & 7) * BN;
  const int m0 = blockIdx.y * BM;

  floatx4 acc[4][4] = {};

  const int row0 = tid >> 2;
  const int colb = (tid & 3) * 16;

  const char* Abase = (const char*)(A + (size_t)m0 * K);
  const char* Bbase = (const char*)(Bw + (size_t)n0 * K);
  char* AsB = (char*)&As[0][0];
  char* BsB = (char*)&Bs[0][0];
  const size_t rowpitch = (size_t)K * 2;

  for (int kb = 0; kb < K; kb += BK) {
#pragma unroll
    for (int i = 0; i < 2; ++i) {
      int r = row0 + i * 64;
      int lo = r * 64 + colb;
      async_copy16(Abase + (size_t)r * rowpitch + (size_t)kb * 2 + colb, AsB + lo);
      async_copy16(Bbase + (size_t)r * rowpitch + (size_t)kb * 2 + colb, BsB + lo);
    }
    __syncthreads();

    bf16x8 afrag[4], bfrag[4];
#pragma unroll
    for (int i = 0; i < 4; ++i) {
      afrag[i] = *(const bf16x8*)&As[wm * 64 + i * 16 + l15][quad * 8];
      bfrag[i] = *(const bf16x8*)&Bs[wn * 64 + i * 16 + l15][quad * 8];
    }
#pragma unroll
    for (int i = 0; i < 4; ++i)
#pragma unroll
      for (int j = 0; j < 4; ++j)
        acc[i][j] = __builtin_amdgcn_mfma_f32_16x16x32_bf16(afrag[i], bfrag[j], acc[i][j], 0, 0, 0);
    __syncthreads();
  }

#pragma unroll
  for (int i = 0; i < 4; ++i) {
#pragma unroll
    for (int j = 0; j < 4; ++j) {
      int row = m0 + wm * 64 + i * 16 + quad * 4;
      int col = n0 + wn * 64 + j * 16 + l15;
      float* Cp = C + (size_t)row * N + col;
#pragma unroll
      for (int r = 0; r < 4; ++r)
        Cp[(size_t)r * N] = acc[i][j][r];
    }
  }
}

// ---------------------------------------------------------------------------
// Output-projection GEMM (generic m97 tile, unchanged from r4).
// ---------------------------------------------------------------------------
__global__ __launch_bounds__(256)
void gemm_bt(const bf16_t* __restrict__ A, const bf16_t* __restrict__ Bw,
             float* __restrict__ C, int M, int N, int K) {
  constexpr int BM = 128, BN = 128, BK = 32;
  __shared__ __align__(16) bf16_t As[BM][BK];
  __shared__ __align__(16) bf16_t Bs[BN][BK];

  const int tid  = threadIdx.x;
  const int lane = tid & 63;
  const int wave = tid >> 6;
  const int wm   = wave >> 1;
  const int wn   = wave & 1;
  const int l15  = lane & 15;
  const int quad = lane >> 4;

  const int n0 = blockIdx.x * BN;
  const int m0 = blockIdx.y * BM;

  floatx4 acc[4][4] = {};

  const int row0 = tid >> 2;
  const int colb = (tid & 3) * 16;

  const char* Abase = (const char*)(A + (size_t)m0 * K);
  const char* Bbase = (const char*)(Bw + (size_t)n0 * K);
  char* AsB = (char*)&As[0][0];
  char* BsB = (char*)&Bs[0][0];
  const size_t rowpitch = (size_t)K * 2;

  for (int kb = 0; kb < K; kb += BK) {
#pragma unroll
    for (int i = 0; i < 2; ++i) {
      int r = row0 + i * 64;
      int lo = r * 64 + colb;
      async_copy16(Abase + (size_t)r * rowpitch + (size_t)kb * 2 + colb, AsB + lo);
      async_copy16(Bbase + (size_t)r * rowpitch + (size_t)kb * 2 + colb, BsB + lo);
    }
    __syncthreads();

    bf16x8 afrag[4], bfrag[4];
#pragma unroll
    for (int i = 0; i < 4; ++i) {
      afrag[i] = *(const bf16x8*)&As[wm * 64 + i * 16 + l15][quad * 8];
      bfrag[i] = *(const bf16x8*)&Bs[wn * 64 + i * 16 + l15][quad * 8];
    }
#pragma unroll
    for (int i = 0; i < 4; ++i)
#pragma unroll
      for (int j = 0; j < 4; ++j)
        acc[i][j] = __builtin_amdgcn_mfma_f32_16x16x32_bf16(afrag[i], bfrag[j], acc[i][j], 0, 0, 0);
    __syncthreads();
  }

#pragma unroll
  for (int i = 0; i < 4; ++i) {
#pragma unroll
    for (int j = 0; j < 4; ++j) {
      int row = m0 + wm * 64 + i * 16 + quad * 4;
      int col = n0 + wn * 64 + j * 16 + l15;
      float* Cp = C + (size_t)row * N + col;
#pragma unroll
      for (int r = 0; r < 4; ++r)
        Cp[(size_t)r * N] = acc[i][j][r];
    }
  }
}

// ---------------------------------------------------------------------------
// Scan pass 1: chunk-local b-scan from -inf. G[bh][chunk][lane]. (= r4 wkv_chunk_b)
// ---------------------------------------------------------------------------
__global__ __launch_bounds__(64)
void wkv_pass1(const float* __restrict__ kbuf, const float* __restrict__ time_decay,
               float* __restrict__ G) {
  __shared__ __align__(16) float ks[CL_][64];
  const int blk   = blockIdx.x;
  const int chunk = blk & (CHUNKS_ - 1);
  const int bh    = blk >> 6;
  const int b = bh >> 4, h = bh & 15;
  const int lane = threadIdx.x;
  const int c = h * HD_ + lane;
  const float w = -__expf(time_decay[c]);

  const size_t gbase = ((size_t)b * S_ + (size_t)chunk * CL_) * D_ + h * HD_;
  const char* kg = (const char*)(kbuf + gbase);
  const int rsel = lane >> 4;
  const int csel = (lane & 15) * 16;
#pragma unroll
  for (int i = 0; i < CL_ / 4; ++i) {
    size_t go = (size_t)(i * 4 + rsel) * (D_ * 4) + csel;
    async_copy16(kg + go, (char*)&ks[0][0] + i * 1024 + lane * 16);
  }
  __builtin_amdgcn_s_waitcnt(0);
  __syncthreads();

  float g = -1e38f;
  for (int t = 0; t < CL_; ++t) {
    float kt = ks[t][lane];
    float ww = g + w;
    float d2 = ww - kt;
    float em = __expf(-fabsf(d2));
    float e1b = (d2 >= 0.0f) ? 1.0f : em;
    float e2b = (d2 >= 0.0f) ? em : 1.0f;
    g = fmaxf(ww, kt) + __logf(e1b + e2b + 1e-8f);
  }
  G[(size_t)bh * (CHUNKS_ * 64) + chunk * 64 + lane] = g;
}

// ---------------------------------------------------------------------------
// Scan pass 2 (= r4 merge_b folded into chunk_a): each block stages the full
// G slab for its bh, computes its own incoming b via the exact LSE prefix
// (same formula as r4's wkv_merge_b), stores si_b, then computes the chunk's
// affine a-transfer (A = prod e1b, Bv = run from 0) exactly as r4 wkv_chunk_a.
// ---------------------------------------------------------------------------
__global__ __launch_bounds__(64)
void wkv_pass2(const float* __restrict__ kbuf, const float* __restrict__ vbuf,
               const float* __restrict__ time_decay, const float* __restrict__ G,
               float* __restrict__ si_b, float* __restrict__ cs_A, float* __restrict__ cs_Bv) {
  __shared__ __align__(16) float Gs[CHUNKS_][64];   // 16 KB
  __shared__ __align__(16) float ks[CL_][64];       // 8 KB
  __shared__ __align__(16) float vs[CL_][64];       // 8 KB
  const int blk   = blockIdx.x;
  const int chunk = blk & (CHUNKS_ - 1);
  const int bh    = blk >> 6;
  const int b = bh >> 4, h = bh & 15;
  const int lane = threadIdx.x;
  const int c = h * HD_ + lane;
  const float w  = -__expf(time_decay[c]);
  const float wL = w * (float)CL_;

  const char* gg = (const char*)(G + (size_t)bh * (CHUNKS_ * 64));
#pragma unroll
  for (int i = 0; i < 16; ++i)
    async_copy16(gg + i * 1024 + lane * 16, (char*)&Gs[0][0] + i * 1024 + lane * 16);

  const size_t gbase = ((size_t)b * S_ + (size_t)chunk * CL_) * D_ + h * HD_;
  const char* kg = (const char*)(kbuf + gbase);
  const char* vg = (const char*)(vbuf + gbase);
  const int rsel = lane >> 4;
  const int csel = (lane & 15) * 16;
#pragma unroll
  for (int i = 0; i < CL_ / 4; ++i) {
    size_t go = (size_t)(i * 4 + rsel) * (D_ * 4) + csel;
    async_copy16(kg + go, (char*)&ks[0][0] + i * 1024 + lane * 16);
    async_copy16(vg + go, (char*)&vs[0][0] + i * 1024 + lane * 16);
  }
  __builtin_amdgcn_s_waitcnt(0);
  __syncthreads();

  // incoming b for this chunk: prefix LSE over chunks [0, chunk)
  float bst = -1e38f;
  for (int ch = 0; ch < chunk; ++ch) {
    float g = Gs[ch][lane];
    float b1 = bst + wL;
    float dd = b1 - g;
    float em = __expf(-fabsf(dd));
    bst = fmaxf(b1, g) + __logf(1.0f + em);
  }
  const size_t so = (size_t)bh * (CHUNKS_ * 64) + chunk * 64 + lane;
  si_b[so] = bst;

  float a = 0.0f, Ap = 1.0f;
  for (int t = 0; t < CL_; ++t) {
    float kt = ks[t][lane], vt = vs[t][lane];
    float ww = bst + w;
    float d2 = ww - kt;
    float em = __expf(-fabsf(d2));
    float e1b = (d2 >= 0.0f) ? 1.0f : em;
    float e2b = (d2 >= 0.0f) ? em : 1.0f;
    a  = e1b * a + e2b * vt;
    Ap = Ap * e1b;
    bst = fmaxf(ww, kt) + __logf(e1b + e2b + 1e-8f);
  }
  cs_A [so] = Ap;
  cs_Bv[so] = a;
}

// ---------------------------------------------------------------------------
// Scan pass 3 (= r4 merge_a folded into wkv_final): stage cs_A/cs_Bv slab,
// compute incoming a via the affine prefix, then run the exact reference
// steps from (a_in, b_in); fuse sigmoid(r)*wkv and GroupNorm partials.
// LDS reused across phases (32 KB total -> 5 blocks/CU).
// ---------------------------------------------------------------------------
__global__ __launch_bounds__(64)
void wkv_pass3(const float* __restrict__ rbuf, const float* __restrict__ kbuf,
               const float* __restrict__ vbuf,
               const float* __restrict__ time_decay, const float* __restrict__ time_first,
               const float* __restrict__ si_b,
               const float* __restrict__ cs_A, const float* __restrict__ cs_Bv,
               float* __restrict__ rwkv, float* __restrict__ psum, float* __restrict__ psq) {
  __shared__ __align__(16) char smem[32 * 1024];
  float (*As_)[64] = (float(*)[64])smem;                 // 16 KB
  float (*Bs_)[64] = (float(*)[64])(smem + 16384);       // 16 KB
  const int blk   = blockIdx.x;
  const int chunk = blk & (CHUNKS_ - 1);
  const int bh    = blk >> 6;
  const int b = bh >> 4, h = bh & 15;
  const int lane = threadIdx.x;
  const int c = h * HD_ + lane;
  const float w = -__expf(time_decay[c]);
  const float u = time_first[c];

  const char* ag = (const char*)(cs_A  + (size_t)bh * (CHUNKS_ * 64));
  const char* bg = (const char*)(cs_Bv + (size_t)bh * (CHUNKS_ * 64));
#pragma unroll
  for (int i = 0; i < 16; ++i) {
    async_copy16(ag + i * 1024 + lane * 16, (char*)&As_[0][0] + i * 1024 + lane * 16);
    async_copy16(bg + i * 1024 + lane * 16, (char*)&Bs_[0][0] + i * 1024 + lane * 16);
  }
  const size_t so = (size_t)bh * (CHUNKS_ * 64) + chunk * 64 + lane;
  float bst = si_b[so];
  __builtin_amdgcn_s_waitcnt(0);
  __syncthreads();

  // incoming a for this chunk: affine prefix over chunks [0, chunk)
  float a = 0.0f;
  for (int ch = 0; ch < chunk; ++ch)
    a = As_[ch][lane] * a + Bs_[ch][lane];
  __syncthreads();   // everyone done with As_/Bs_ before LDS reuse

  // reuse LDS for r/k/v chunk slabs (24 KB of the 32)
  float (*rs)[64] = (float(*)[64])smem;
  float (*ks)[64] = (float(*)[64])(smem + 8192);
  float (*vs)[64] = (float(*)[64])(smem + 16384);
  const size_t gbase = ((size_t)b * S_ + (size_t)chunk * CL_) * D_ + h * HD_;
  const char* rg = (const char*)(rbuf + gbase);
  const char* kg = (const char*)(kbuf + gbase);
  const char* vg = (const char*)(vbuf + gbase);
  const int rsel = lane >> 4;
  const int csel = (lane & 15) * 16;
#pragma unroll
  for (int i = 0; i < CL_ / 4; ++i) {
    size_t go = (size_t)(i * 4 + rsel) * (D_ * 4) + csel;
    async_copy16(rg + go, (char*)&rs[0][0] + i * 1024 + lane * 16);
    async_copy16(kg + go, (char*)&ks[0][0] + i * 1024 + lane * 16);
    async_copy16(vg + go, (char*)&vs[0][0] + i * 1024 + lane * 16);
  }
  __builtin_amdgcn_s_waitcnt(0);
  __syncthreads();

  float sum = 0.0f, sq = 0.0f;
  size_t widx = gbase + lane;
  for (int t = 0; t < CL_; ++t) {
    float kt = ks[t][lane], vt = vs[t][lane], rt = rs[t][lane];
    float wk = kt + u;
    float d1 = bst - wk;
    float em1 = __expf(-fabsf(d1));
    float e1 = (d1 >= 0.0f) ? 1.0f : em1;
    float e2 = (d1 >= 0.0f) ? em1 : 1.0f;
    float out = __fdividef(e1 * a + e2 * vt, e1 + e2 + 1e-8f);

    float ww = bst + w;
    float d2 = ww - kt;
    float em2 = __expf(-fabsf(d2));
    float e1b = (d2 >= 0.0f) ? 1.0f : em2;
    float e2b = (d2 >= 0.0f) ? em2 : 1.0f;
    a   = e1b * a + e2b * vt;
    bst = fmaxf(ww, kt) + __logf(e1b + e2b + 1e-8f);

    float sig = __fdividef(1.0f, 1.0f + __expf(-rt));
    float o2 = sig * out;
    rwkv[widx] = o2;
    sum += o2; sq += o2 * o2;
    widx += D_;
  }

#pragma unroll
  for (int off = 32; off > 0; off >>= 1) {
    sum += __shfl_down(sum, off);
    sq  += __shfl_down(sq, off);
  }
  if (lane == 0) {
    psum[bh * CHUNKS_ + chunk] = sum;
    psq [bh * CHUNKS_ + chunk] = sq;
  }
}

// ---------------------------------------------------------------------------
// GroupNorm: stats finalize fused into apply+cast. Each 256-thread block
// spans d-range of 256 = 4 heads; wave j reduces the 64 partials of head j.
// ---------------------------------------------------------------------------
__global__ __launch_bounds__(256)
void norm_cast(const float* __restrict__ rwkv,
               const float* __restrict__ psum, const float* __restrict__ psq,
               const float* __restrict__ gamma, const float* __restrict__ beta,
               bf16_t* __restrict__ normed) {
  __shared__ float smean[4], srstd[4];
  const int tid = threadIdx.x;
  const int lane = tid & 63;
  const int wj = tid >> 6;                         // 0..3, == head slot in block
  int idx0 = blockIdx.x * 256;                     // aligned to 256 -> same (b,t)
  int d0 = idx0 & (D_ - 1);
  int bb = idx0 / (S_ * D_);
  int bh = bb * H_ + (d0 >> 6) + wj;

  float s = psum[bh * CHUNKS_ + lane];
  float q = psq [bh * CHUNKS_ + lane];
#pragma unroll
  for (int off = 32; off > 0; off >>= 1) {
    s += __shfl_down(s, off);
    q += __shfl_down(q, off);
  }
  if (lane == 0) {
    const float n = (float)(S_ * HD_);
    float mean = s / n;
    float var  = q / n - mean * mean;
    smean[wj] = mean;
    srstd[wj] = rsqrtf(var + 1e-5f);
  }
  __syncthreads();

  int idx = idx0 + tid;
  int d = idx & (D_ - 1);
  float v = (rwkv[idx] - smean[wj]) * srstd[wj] * gamma[d] + beta[d];
  normed[idx] = (bf16_t)v;
}

// ---------------------------------------------------------------------------
extern "C" void kernel_launch(void* const* d_in, const int* in_sizes, int n_in,
                              void* d_out, int out_size, void* d_ws, size_t ws_size,
                              hipStream_t stream) {
  const float* x     = (const float*)d_in[0];
  const float* tmr   = (const float*)d_in[1];
  const float* tmk   = (const float*)d_in[2];
  const float* tmv   = (const float*)d_in[3];
  const float* Wr    = (const float*)d_in[4];
  const float* Wk    = (const float*)d_in[5];
  const float* Wv    = (const float*)d_in[6];
  const float* Wo    = (const float*)d_in[7];
  const float* td    = (const float*)d_in[8];
  const float* tf    = (const float*)d_in[9];
  const float* gamma = (const float*)d_in[10];
  const float* beta  = (const float*)d_in[11];

  char* ws = (char*)d_ws;
  const size_t MB = 1024 * 1024;
  bf16_t* W_bf   = (bf16_t*)(ws + 0 * MB);     // Wr,Wk,Wv,Wo bf16, contiguous
  bf16_t* Wo_bf  = (bf16_t*)(ws + 6 * MB);
  bf16_t* xr     = (bf16_t*)(ws + 8 * MB);     // 16MB each
  bf16_t* xk     = (bf16_t*)(ws + 24 * MB);
  bf16_t* xv     = (bf16_t*)(ws + 40 * MB);
  float*  rbuf   = (float*)(ws + 56 * MB);     // 32MB each
  float*  kbuf   = (float*)(ws + 88 * MB);
  float*  vbuf   = (float*)(ws + 120 * MB);
  // scan scratch reuses the xk region (dead after gemm3). 1MB per array.
  float*  G      = (float*)(ws + 24 * MB);
  float*  cs_A   = (float*)(ws + 25 * MB);
  float*  cs_Bv  = (float*)(ws + 26 * MB);
  float*  si_b   = (float*)(ws + 27 * MB);
  float*  psum   = (float*)(ws + 28 * MB);     // 16 KB each
  float*  psq    = (float*)(ws + 28 * MB + 64 * 1024);
  bf16_t* normed = xr;                         // xr dead after gemm3

  float* rwkv = (float*)d_out;                 // d_out doubles as fp32 scratch
  float* outp = (float*)d_out;

  // 1: cast + mix (12M threads)
  pre_kernel<<<(12 * 1024 * 1024) / 256, 256, 0, stream>>>(
      Wr, Wk, Wv, Wo, W_bf, x, tmr, tmk, tmv, xr, xk, xv);

  // 2: fused r/k/v projections
  gemm3<<<dim3(24, 64), 256, 0, stream>>>(xr, xk, xv, W_bf, rbuf, kbuf, vbuf);

  // 3-5: chunked WKV scan
  wkv_pass1<<<B_ * H_ * CHUNKS_, 64, 0, stream>>>(kbuf, td, G);
  wkv_pass2<<<B_ * H_ * CHUNKS_, 64, 0, stream>>>(kbuf, vbuf, td, G, si_b, cs_A, cs_Bv);
  wkv_pass3<<<B_ * H_ * CHUNKS_, 64, 0, stream>>>(rbuf, kbuf, vbuf, td, tf,
                                                  si_b, cs_A, cs_Bv, rwkv, psum, psq);

  // 6: GroupNorm (stats + apply + cast)
  norm_cast<<<(M_ * D_) / 256, 256, 0, stream>>>(rwkv, psum, psq, gamma, beta, normed);

  // 7: output projection
  gemm_bt<<<dim3(D_ / 128, M_ / 128), 256, 0, stream>>>(normed, Wo_bf, outp, M_, D_, D_);
}

// Round 6
// 342.605 us; speedup vs baseline: 1.0445x; 1.0445x over previous
//
#include <hip/hip_runtime.h>
#include <cstdint>
#include <cstddef>

#define B_  4
#define S_  2048
#define D_  1024
#define H_  16
#define HD_ 64
#define M_  (B_ * S_)   // 8192 rows

#define CHUNKS_ 64      // parallel chunks per (b,h) sequence
#define CL_     32      // chunk length; CHUNKS_*CL_ == S_

typedef __bf16 bf16_t;
typedef bf16_t bf16x8 __attribute__((ext_vector_type(8)));
typedef float  floatx4 __attribute__((ext_vector_type(4)));

// ---------------------------------------------------------------------------
// async 16B global -> LDS copy (gfx950). LDS dest is wave-uniform base +
// lane*16 (m104/m108); all uses below pass lds = base + lane*16 exactly.
// ---------------------------------------------------------------------------
__device__ __forceinline__ void async_copy16(const void* gmem, void* lds) {
  __builtin_amdgcn_global_load_lds(
      (__attribute__((address_space(1))) void*)const_cast<void*>(gmem),
      (__attribute__((address_space(3))) void*)lds,
      16, 0, 0);
}

// ---------------------------------------------------------------------------
// Fused prologue: weight fp32->bf16 cast (4M elems) + token-shift mix (8M).
// ---------------------------------------------------------------------------
__global__ void pre_kernel(const float* __restrict__ w0, const float* __restrict__ w1,
                           const float* __restrict__ w2, const float* __restrict__ w3,
                           bf16_t* __restrict__ wout,
                           const float* __restrict__ x,
                           const float* __restrict__ tmr, const float* __restrict__ tmk,
                           const float* __restrict__ tmv,
                           bf16_t* __restrict__ xr, bf16_t* __restrict__ xk,
                           bf16_t* __restrict__ xv) {
  const int ONE_M = 1 << 20;
  int gid = blockIdx.x * blockDim.x + threadIdx.x;
  if (gid < 4 * ONE_M) {
    const float* src = (gid < ONE_M) ? w0 : (gid < 2 * ONE_M) ? w1 : (gid < 3 * ONE_M) ? w2 : w3;
    wout[gid] = (bf16_t)src[gid & (ONE_M - 1)];
  } else {
    int idx = gid - 4 * ONE_M;                 // 0 .. 8M-1
    int d = idx & (D_ - 1);
    int t = (idx / D_) & (S_ - 1);
    float xc = x[idx];
    float xp = (t == 0) ? 0.0f : x[idx - D_];
    float mr = tmr[d], mk = tmk[d], mv = tmv[d];
    xr[idx] = (bf16_t)(xc * mr + xp * (1.0f - mr));
    xk[idx] = (bf16_t)(xc * mk + xp * (1.0f - mk));
    xv[idx] = (bf16_t)(xc * mv + xp * (1.0f - mv));
  }
}

// ---------------------------------------------------------------------------
// Fused 3-projection GEMM with XCD-aware swizzle. r5 counters: FETCH 205 MB
// vs 54 ideal — the 8 n-blocks sharing an A-panel landed on 8 different XCDs.
// Remap so each XCD owns whole (proj,m) A-panels and sweeps n locally:
//   flat = x + 24y; xcd = flat&7; j = flat>>3;
//   pair = xcd*24 + (j>>3); n = j&7; proj = pair/64; m = pair%64.
// ---------------------------------------------------------------------------
__global__ __launch_bounds__(256)
void gemm3(const bf16_t* __restrict__ xr, const bf16_t* __restrict__ xk,
           const bf16_t* __restrict__ xv, const bf16_t* __restrict__ Wall,
           float* __restrict__ rbuf, float* __restrict__ kbuf, float* __restrict__ vbuf) {
  constexpr int BM = 128, BN = 128, BK = 32, K = D_, N = D_;
  __shared__ __align__(16) bf16_t As[BM][BK];
  __shared__ __align__(16) bf16_t Bs[BN][BK];

  const int flat = blockIdx.x + 24 * blockIdx.y;   // 0..1535
  const int xcd  = flat & 7;
  const int j    = flat >> 3;                      // 0..191
  const int pair = xcd * 24 + (j >> 3);            // 0..191
  const int nb   = j & 7;
  const int proj = pair / 64;
  const int mb   = pair % 64;

  const bf16_t* A  = (proj == 0) ? xr : (proj == 1) ? xk : xv;
  const bf16_t* Bw = Wall + (size_t)proj * (1 << 20);
  float* C         = (proj == 0) ? rbuf : (proj == 1) ? kbuf : vbuf;

  const int tid  = threadIdx.x;
  const int lane = tid & 63;
  const int wave = tid >> 6;
  const int wm   = wave >> 1;
  const int wn   = wave & 1;
  const int l15  = lane & 15;
  const int quad = lane >> 4;

  const int n0 = nb * BN;
  const int m0 = mb * BM;

  floatx4 acc[4][4] = {};

  const int row0 = tid >> 2;
  const int colb = (tid & 3) * 16;

  const char* Abase = (const char*)(A + (size_t)m0 * K);
  const char* Bbase = (const char*)(Bw + (size_t)n0 * K);
  char* AsB = (char*)&As[0][0];
  char* BsB = (char*)&Bs[0][0];
  const size_t rowpitch = (size_t)K * 2;

  for (int kb = 0; kb < K; kb += BK) {
#pragma unroll
    for (int i = 0; i < 2; ++i) {
      int r = row0 + i * 64;
      int lo = r * 64 + colb;
      async_copy16(Abase + (size_t)r * rowpitch + (size_t)kb * 2 + colb, AsB + lo);
      async_copy16(Bbase + (size_t)r * rowpitch + (size_t)kb * 2 + colb, BsB + lo);
    }
    __syncthreads();

    bf16x8 afrag[4], bfrag[4];
#pragma unroll
    for (int i = 0; i < 4; ++i) {
      afrag[i] = *(const bf16x8*)&As[wm * 64 + i * 16 + l15][quad * 8];
      bfrag[i] = *(const bf16x8*)&Bs[wn * 64 + i * 16 + l15][quad * 8];
    }
#pragma unroll
    for (int i = 0; i < 4; ++i)
#pragma unroll
      for (int jj = 0; jj < 4; ++jj)
        acc[i][jj] = __builtin_amdgcn_mfma_f32_16x16x32_bf16(afrag[i], bfrag[jj], acc[i][jj], 0, 0, 0);
    __syncthreads();
  }

#pragma unroll
  for (int i = 0; i < 4; ++i) {
#pragma unroll
    for (int jj = 0; jj < 4; ++jj) {
      int row = m0 + wm * 64 + i * 16 + quad * 4;
      int col = n0 + wn * 64 + jj * 16 + l15;
      float* Cp = C + (size_t)row * N + col;
#pragma unroll
      for (int r = 0; r < 4; ++r)
        Cp[(size_t)r * N] = acc[i][jj][r];
    }
  }
}

// ---------------------------------------------------------------------------
// Output-projection GEMM, same XCD swizzle (M=8192, N=K=1024 fixed shape).
//   flat = x + 8y; xcd = flat&7; j = flat>>3; m = xcd*8 + (j>>3); n = j&7.
// ---------------------------------------------------------------------------
__global__ __launch_bounds__(256)
void gemm_bt(const bf16_t* __restrict__ A, const bf16_t* __restrict__ Bw,
             float* __restrict__ C) {
  constexpr int BM = 128, BN = 128, BK = 32, K = D_, N = D_;
  __shared__ __align__(16) bf16_t As[BM][BK];
  __shared__ __align__(16) bf16_t Bs[BN][BK];

  const int flat = blockIdx.x + 8 * blockIdx.y;    // 0..511
  const int xcd  = flat & 7;
  const int j    = flat >> 3;                      // 0..63
  const int mb   = xcd * 8 + (j >> 3);             // 0..63
  const int nb   = j & 7;

  const int tid  = threadIdx.x;
  const int lane = tid & 63;
  const int wave = tid >> 6;
  const int wm   = wave >> 1;
  const int wn   = wave & 1;
  const int l15  = lane & 15;
  const int quad = lane >> 4;

  const int n0 = nb * BN;
  const int m0 = mb * BM;

  floatx4 acc[4][4] = {};

  const int row0 = tid >> 2;
  const int colb = (tid & 3) * 16;

  const char* Abase = (const char*)(A + (size_t)m0 * K);
  const char* Bbase = (const char*)(Bw + (size_t)n0 * K);
  char* AsB = (char*)&As[0][0];
  char* BsB = (char*)&Bs[0][0];
  const size_t rowpitch = (size_t)K * 2;

  for (int kb = 0; kb < K; kb += BK) {
#pragma unroll
    for (int i = 0; i < 2; ++i) {
      int r = row0 + i * 64;
      int lo = r * 64 + colb;
      async_copy16(Abase + (size_t)r * rowpitch + (size_t)kb * 2 + colb, AsB + lo);
      async_copy16(Bbase + (size_t)r * rowpitch + (size_t)kb * 2 + colb, BsB + lo);
    }
    __syncthreads();

    bf16x8 afrag[4], bfrag[4];
#pragma unroll
    for (int i = 0; i < 4; ++i) {
      afrag[i] = *(const bf16x8*)&As[wm * 64 + i * 16 + l15][quad * 8];
      bfrag[i] = *(const bf16x8*)&Bs[wn * 64 + i * 16 + l15][quad * 8];
    }
#pragma unroll
    for (int i = 0; i < 4; ++i)
#pragma unroll
      for (int jj = 0; jj < 4; ++jj)
        acc[i][jj] = __builtin_amdgcn_mfma_f32_16x16x32_bf16(afrag[i], bfrag[jj], acc[i][jj], 0, 0, 0);
    __syncthreads();
  }

#pragma unroll
  for (int i = 0; i < 4; ++i) {
#pragma unroll
    for (int jj = 0; jj < 4; ++jj) {
      int row = m0 + wm * 64 + i * 16 + quad * 4;
      int col = n0 + wn * 64 + jj * 16 + l15;
      float* Cp = C + (size_t)row * N + col;
#pragma unroll
      for (int r = 0; r < 4; ++r)
        Cp[(size_t)r * N] = acc[i][jj][r];
    }
  }
}

// ---------------------------------------------------------------------------
// Scan pass 1: chunk-local b-scan from -inf. G[bh][chunk][lane].
// ---------------------------------------------------------------------------
__global__ __launch_bounds__(64)
void wkv_pass1(const float* __restrict__ kbuf, const float* __restrict__ time_decay,
               float* __restrict__ G) {
  __shared__ __align__(16) float ks[CL_][64];
  const int blk   = blockIdx.x;
  const int chunk = blk & (CHUNKS_ - 1);
  const int bh    = blk >> 6;
  const int b = bh >> 4, h = bh & 15;
  const int lane = threadIdx.x;
  const int c = h * HD_ + lane;
  const float w = -__expf(time_decay[c]);

  const size_t gbase = ((size_t)b * S_ + (size_t)chunk * CL_) * D_ + h * HD_;
  const char* kg = (const char*)(kbuf + gbase);
  const int rsel = lane >> 4;
  const int csel = (lane & 15) * 16;
#pragma unroll
  for (int i = 0; i < CL_ / 4; ++i) {
    size_t go = (size_t)(i * 4 + rsel) * (D_ * 4) + csel;
    async_copy16(kg + go, (char*)&ks[0][0] + i * 1024 + lane * 16);
  }
  __builtin_amdgcn_s_waitcnt(0);
  __syncthreads();

  float g = -1e38f;
  for (int t = 0; t < CL_; ++t) {
    float kt = ks[t][lane];
    float ww = g + w;
    float d2 = ww - kt;
    float em = __expf(-fabsf(d2));
    float e1b = (d2 >= 0.0f) ? 1.0f : em;
    float e2b = (d2 >= 0.0f) ? em : 1.0f;
    g = fmaxf(ww, kt) + __logf(e1b + e2b + 1e-8f);
  }
  G[(size_t)bh * (CHUNKS_ * 64) + chunk * 64 + lane] = g;
}

// ---------------------------------------------------------------------------
// Scan pass 2: stage G slab, compute incoming b via exact LSE prefix, store
// si_b, then the chunk's affine a-transfer (A = prod e1b, Bv = run from 0).
// ---------------------------------------------------------------------------
__global__ __launch_bounds__(64)
void wkv_pass2(const float* __restrict__ kbuf, const float* __restrict__ vbuf,
               const float* __restrict__ time_decay, const float* __restrict__ G,
               float* __restrict__ si_b, float* __restrict__ cs_A, float* __restrict__ cs_Bv) {
  __shared__ __align__(16) float Gs[CHUNKS_][64];   // 16 KB
  __shared__ __align__(16) float ks[CL_][64];       // 8 KB
  __shared__ __align__(16) float vs[CL_][64];       // 8 KB
  const int blk   = blockIdx.x;
  const int chunk = blk & (CHUNKS_ - 1);
  const int bh    = blk >> 6;
  const int b = bh >> 4, h = bh & 15;
  const int lane = threadIdx.x;
  const int c = h * HD_ + lane;
  const float w  = -__expf(time_decay[c]);
  const float wL = w * (float)CL_;

  const char* gg = (const char*)(G + (size_t)bh * (CHUNKS_ * 64));
#pragma unroll
  for (int i = 0; i < 16; ++i)
    async_copy16(gg + i * 1024 + lane * 16, (char*)&Gs[0][0] + i * 1024 + lane * 16);

  const size_t gbase = ((size_t)b * S_ + (size_t)chunk * CL_) * D_ + h * HD_;
  const char* kg = (const char*)(kbuf + gbase);
  const char* vg = (const char*)(vbuf + gbase);
  const int rsel = lane >> 4;
  const int csel = (lane & 15) * 16;
#pragma unroll
  for (int i = 0; i < CL_ / 4; ++i) {
    size_t go = (size_t)(i * 4 + rsel) * (D_ * 4) + csel;
    async_copy16(kg + go, (char*)&ks[0][0] + i * 1024 + lane * 16);
    async_copy16(vg + go, (char*)&vs[0][0] + i * 1024 + lane * 16);
  }
  __builtin_amdgcn_s_waitcnt(0);
  __syncthreads();

  float bst = -1e38f;
  for (int ch = 0; ch < chunk; ++ch) {
    float g = Gs[ch][lane];
    float b1 = bst + wL;
    float dd = b1 - g;
    float em = __expf(-fabsf(dd));
    bst = fmaxf(b1, g) + __logf(1.0f + em);
  }
  const size_t so = (size_t)bh * (CHUNKS_ * 64) + chunk * 64 + lane;
  si_b[so] = bst;

  float a = 0.0f, Ap = 1.0f;
  for (int t = 0; t < CL_; ++t) {
    float kt = ks[t][lane], vt = vs[t][lane];
    float ww = bst + w;
    float d2 = ww - kt;
    float em = __expf(-fabsf(d2));
    float e1b = (d2 >= 0.0f) ? 1.0f : em;
    float e2b = (d2 >= 0.0f) ? em : 1.0f;
    a  = e1b * a + e2b * vt;
    Ap = Ap * e1b;
    bst = fmaxf(ww, kt) + __logf(e1b + e2b + 1e-8f);
  }
  cs_A [so] = Ap;
  cs_Bv[so] = a;
}

// ---------------------------------------------------------------------------
// Scan pass 3: affine prefix for incoming a, then exact reference steps;
// fuse sigmoid(r)*wkv and GroupNorm partials. LDS reused across phases.
// ---------------------------------------------------------------------------
__global__ __launch_bounds__(64)
void wkv_pass3(const float* __restrict__ rbuf, const float* __restrict__ kbuf,
               const float* __restrict__ vbuf,
               const float* __restrict__ time_decay, const float* __restrict__ time_first,
               const float* __restrict__ si_b,
               const float* __restrict__ cs_A, const float* __restrict__ cs_Bv,
               float* __restrict__ rwkv, float* __restrict__ psum, float* __restrict__ psq) {
  __shared__ __align__(16) char smem[32 * 1024];
  float (*As_)[64] = (float(*)[64])smem;                 // 16 KB
  float (*Bs_)[64] = (float(*)[64])(smem + 16384);       // 16 KB
  const int blk   = blockIdx.x;
  const int chunk = blk & (CHUNKS_ - 1);
  const int bh    = blk >> 6;
  const int b = bh >> 4, h = bh & 15;
  const int lane = threadIdx.x;
  const int c = h * HD_ + lane;
  const float w = -__expf(time_decay[c]);
  const float u = time_first[c];

  const char* ag = (const char*)(cs_A  + (size_t)bh * (CHUNKS_ * 64));
  const char* bg = (const char*)(cs_Bv + (size_t)bh * (CHUNKS_ * 64));
#pragma unroll
  for (int i = 0; i < 16; ++i) {
    async_copy16(ag + i * 1024 + lane * 16, (char*)&As_[0][0] + i * 1024 + lane * 16);
    async_copy16(bg + i * 1024 + lane * 16, (char*)&Bs_[0][0] + i * 1024 + lane * 16);
  }
  const size_t so = (size_t)bh * (CHUNKS_ * 64) + chunk * 64 + lane;
  float bst = si_b[so];
  __builtin_amdgcn_s_waitcnt(0);
  __syncthreads();

  float a = 0.0f;
  for (int ch = 0; ch < chunk; ++ch)
    a = As_[ch][lane] * a + Bs_[ch][lane];
  __syncthreads();   // done with As_/Bs_ before LDS reuse

  float (*rs)[64] = (float(*)[64])smem;
  float (*ks)[64] = (float(*)[64])(smem + 8192);
  float (*vs)[64] = (float(*)[64])(smem + 16384);
  const size_t gbase = ((size_t)b * S_ + (size_t)chunk * CL_) * D_ + h * HD_;
  const char* rg = (const char*)(rbuf + gbase);
  const char* kg = (const char*)(kbuf + gbase);
  const char* vg = (const char*)(vbuf + gbase);
  const int rsel = lane >> 4;
  const int csel = (lane & 15) * 16;
#pragma unroll
  for (int i = 0; i < CL_ / 4; ++i) {
    size_t go = (size_t)(i * 4 + rsel) * (D_ * 4) + csel;
    async_copy16(rg + go, (char*)&rs[0][0] + i * 1024 + lane * 16);
    async_copy16(kg + go, (char*)&ks[0][0] + i * 1024 + lane * 16);
    async_copy16(vg + go, (char*)&vs[0][0] + i * 1024 + lane * 16);
  }
  __builtin_amdgcn_s_waitcnt(0);
  __syncthreads();

  float sum = 0.0f, sq = 0.0f;
  size_t widx = gbase + lane;
  for (int t = 0; t < CL_; ++t) {
    float kt = ks[t][lane], vt = vs[t][lane], rt = rs[t][lane];
    float wk = kt + u;
    float d1 = bst - wk;
    float em1 = __expf(-fabsf(d1));
    float e1 = (d1 >= 0.0f) ? 1.0f : em1;
    float e2 = (d1 >= 0.0f) ? em1 : 1.0f;
    float out = __fdividef(e1 * a + e2 * vt, e1 + e2 + 1e-8f);

    float ww = bst + w;
    float d2 = ww - kt;
    float em2 = __expf(-fabsf(d2));
    float e1b = (d2 >= 0.0f) ? 1.0f : em2;
    float e2b = (d2 >= 0.0f) ? em2 : 1.0f;
    a   = e1b * a + e2b * vt;
    bst = fmaxf(ww, kt) + __logf(e1b + e2b + 1e-8f);

    float sig = __fdividef(1.0f, 1.0f + __expf(-rt));
    float o2 = sig * out;
    rwkv[widx] = o2;
    sum += o2; sq += o2 * o2;
    widx += D_;
  }

#pragma unroll
  for (int off = 32; off > 0; off >>= 1) {
    sum += __shfl_down(sum, off);
    sq  += __shfl_down(sq, off);
  }
  if (lane == 0) {
    psum[bh * CHUNKS_ + chunk] = sum;
    psq [bh * CHUNKS_ + chunk] = sq;
  }
}

// ---------------------------------------------------------------------------
// GroupNorm: stats finalize fused into apply+cast.
// ---------------------------------------------------------------------------
__global__ __launch_bounds__(256)
void norm_cast(const float* __restrict__ rwkv,
               const float* __restrict__ psum, const float* __restrict__ psq,
               const float* __restrict__ gamma, const float* __restrict__ beta,
               bf16_t* __restrict__ normed) {
  __shared__ float smean[4], srstd[4];
  const int tid = threadIdx.x;
  const int lane = tid & 63;
  const int wj = tid >> 6;
  int idx0 = blockIdx.x * 256;
  int d0 = idx0 & (D_ - 1);
  int bb = idx0 / (S_ * D_);
  int bh = bb * H_ + (d0 >> 6) + wj;

  float s = psum[bh * CHUNKS_ + lane];
  float q = psq [bh * CHUNKS_ + lane];
#pragma unroll
  for (int off = 32; off > 0; off >>= 1) {
    s += __shfl_down(s, off);
    q += __shfl_down(q, off);
  }
  if (lane == 0) {
    const float n = (float)(S_ * HD_);
    float mean = s / n;
    float var  = q / n - mean * mean;
    smean[wj] = mean;
    srstd[wj] = rsqrtf(var + 1e-5f);
  }
  __syncthreads();

  int idx = idx0 + tid;
  int d = idx & (D_ - 1);
  float v = (rwkv[idx] - smean[wj]) * srstd[wj] * gamma[d] + beta[d];
  normed[idx] = (bf16_t)v;
}

// ---------------------------------------------------------------------------
extern "C" void kernel_launch(void* const* d_in, const int* in_sizes, int n_in,
                              void* d_out, int out_size, void* d_ws, size_t ws_size,
                              hipStream_t stream) {
  const float* x     = (const float*)d_in[0];
  const float* tmr   = (const float*)d_in[1];
  const float* tmk   = (const float*)d_in[2];
  const float* tmv   = (const float*)d_in[3];
  const float* Wr    = (const float*)d_in[4];
  const float* Wk    = (const float*)d_in[5];
  const float* Wv    = (const float*)d_in[6];
  const float* Wo    = (const float*)d_in[7];
  const float* td    = (const float*)d_in[8];
  const float* tf    = (const float*)d_in[9];
  const float* gamma = (const float*)d_in[10];
  const float* beta  = (const float*)d_in[11];

  char* ws = (char*)d_ws;
  const size_t MB = 1024 * 1024;
  bf16_t* W_bf   = (bf16_t*)(ws + 0 * MB);     // Wr,Wk,Wv,Wo bf16, contiguous
  bf16_t* Wo_bf  = (bf16_t*)(ws + 6 * MB);
  bf16_t* xr     = (bf16_t*)(ws + 8 * MB);     // 16MB each
  bf16_t* xk     = (bf16_t*)(ws + 24 * MB);
  bf16_t* xv     = (bf16_t*)(ws + 40 * MB);
  float*  rbuf   = (float*)(ws + 56 * MB);     // 32MB each
  float*  kbuf   = (float*)(ws + 88 * MB);
  float*  vbuf   = (float*)(ws + 120 * MB);
  float*  G      = (float*)(ws + 24 * MB);     // scan scratch reuses xk region
  float*  cs_A   = (float*)(ws + 25 * MB);
  float*  cs_Bv  = (float*)(ws + 26 * MB);
  float*  si_b   = (float*)(ws + 27 * MB);
  float*  psum   = (float*)(ws + 28 * MB);
  float*  psq    = (float*)(ws + 28 * MB + 64 * 1024);
  bf16_t* normed = xr;                         // xr dead after gemm3

  float* rwkv = (float*)d_out;                 // d_out doubles as fp32 scratch
  float* outp = (float*)d_out;

  pre_kernel<<<(12 * 1024 * 1024) / 256, 256, 0, stream>>>(
      Wr, Wk, Wv, Wo, W_bf, x, tmr, tmk, tmv, xr, xk, xv);

  gemm3<<<dim3(24, 64), 256, 0, stream>>>(xr, xk, xv, W_bf, rbuf, kbuf, vbuf);

  wkv_pass1<<<B_ * H_ * CHUNKS_, 64, 0, stream>>>(kbuf, td, G);
  wkv_pass2<<<B_ * H_ * CHUNKS_, 64, 0, stream>>>(kbuf, vbuf, td, G, si_b, cs_A, cs_Bv);
  wkv_pass3<<<B_ * H_ * CHUNKS_, 64, 0, stream>>>(rbuf, kbuf, vbuf, td, tf,
                                                  si_b, cs_A, cs_Bv, rwkv, psum, psq);

  norm_cast<<<(M_ * D_) / 256, 256, 0, stream>>>(rwkv, psum, psq, gamma, beta, normed);

  gemm_bt<<<dim3(8, 64), 256, 0, stream>>>(normed, Wo_bf, outp);
}

// Round 7
// 319.144 us; speedup vs baseline: 1.1213x; 1.0735x over previous
//
#include <hip/hip_runtime.h>
#include <cstdint>
#include <cstddef>

#define B_  4
#define S_  2048
#define D_  1024
#define H_  16
#define HD_ 64
#define M_  (B_ * S_)   // 8192 rows

#define CHUNKS_ 64      // parallel chunks per (b,h) sequence
#define CL_     32      // chunk length; CHUNKS_*CL_ == S_

typedef __bf16 bf16_t;
typedef bf16_t bf16x8 __attribute__((ext_vector_type(8)));
typedef float  floatx4 __attribute__((ext_vector_type(4)));

// ---------------------------------------------------------------------------
// async 16B global -> LDS copy (gfx950). LDS dest is wave-uniform base +
// lane*16 (m104/m108); all uses below pass lds = base + lane*16 exactly.
// ---------------------------------------------------------------------------
__device__ __forceinline__ void async_copy16(const void* gmem, void* lds) {
  __builtin_amdgcn_global_load_lds(
      (__attribute__((address_space(1))) void*)const_cast<void*>(gmem),
      (__attribute__((address_space(3))) void*)lds,
      16, 0, 0);
}

// ---------------------------------------------------------------------------
// Fused prologue: weight fp32->bf16 cast (4M elems) + token-shift mix (8M).
// ---------------------------------------------------------------------------
__global__ void pre_kernel(const float* __restrict__ w0, const float* __restrict__ w1,
                           const float* __restrict__ w2, const float* __restrict__ w3,
                           bf16_t* __restrict__ wout,
                           const float* __restrict__ x,
                           const float* __restrict__ tmr, const float* __restrict__ tmk,
                           const float* __restrict__ tmv,
                           bf16_t* __restrict__ xr, bf16_t* __restrict__ xk,
                           bf16_t* __restrict__ xv) {
  const int ONE_M = 1 << 20;
  int gid = blockIdx.x * blockDim.x + threadIdx.x;
  if (gid < 4 * ONE_M) {
    const float* src = (gid < ONE_M) ? w0 : (gid < 2 * ONE_M) ? w1 : (gid < 3 * ONE_M) ? w2 : w3;
    wout[gid] = (bf16_t)src[gid & (ONE_M - 1)];
  } else {
    int idx = gid - 4 * ONE_M;                 // 0 .. 8M-1
    int d = idx & (D_ - 1);
    int t = (idx / D_) & (S_ - 1);
    float xc = x[idx];
    float xp = (t == 0) ? 0.0f : x[idx - D_];
    float mr = tmr[d], mk = tmk[d], mv = tmv[d];
    xr[idx] = (bf16_t)(xc * mr + xp * (1.0f - mr));
    xk[idx] = (bf16_t)(xc * mk + xp * (1.0f - mk));
    xv[idx] = (bf16_t)(xc * mv + xp * (1.0f - mv));
  }
}

// ---------------------------------------------------------------------------
// Fused 3-projection GEMM. XCD swizzle (r6: FETCH 205->49 MB) + double-
// buffered LDS prefetch (r7): stage k+1 BEFORE computing k, one barrier per
// iteration, so the vmcnt(0) drain at the barrier only pays the residual of
// the load latency not covered by the ds_read+MFMA phase.
// ---------------------------------------------------------------------------
__global__ __launch_bounds__(256)
void gemm3(const bf16_t* __restrict__ xr, const bf16_t* __restrict__ xk,
           const bf16_t* __restrict__ xv, const bf16_t* __restrict__ Wall,
           float* __restrict__ rbuf, float* __restrict__ kbuf, float* __restrict__ vbuf) {
  constexpr int BM = 128, BN = 128, BK = 32, K = D_, N = D_;
  __shared__ __align__(16) bf16_t As[2][BM][BK];   // 2 x 8 KB
  __shared__ __align__(16) bf16_t Bs[2][BN][BK];   // 2 x 8 KB

  const int flat = blockIdx.x + 24 * blockIdx.y;   // 0..1535
  const int xcd  = flat & 7;
  const int j    = flat >> 3;                      // 0..191
  const int pair = xcd * 24 + (j >> 3);            // 0..191
  const int nb   = j & 7;
  const int proj = pair / 64;
  const int mb   = pair % 64;

  const bf16_t* A  = (proj == 0) ? xr : (proj == 1) ? xk : xv;
  const bf16_t* Bw = Wall + (size_t)proj * (1 << 20);
  float* C         = (proj == 0) ? rbuf : (proj == 1) ? kbuf : vbuf;

  const int tid  = threadIdx.x;
  const int lane = tid & 63;
  const int wave = tid >> 6;
  const int wm   = wave >> 1;
  const int wn   = wave & 1;
  const int l15  = lane & 15;
  const int quad = lane >> 4;

  const int n0 = nb * BN;
  const int m0 = mb * BM;

  floatx4 acc[4][4] = {};

  const int row0 = tid >> 2;
  const int colb = (tid & 3) * 16;

  const char* Abase = (const char*)(A + (size_t)m0 * K);
  const char* Bbase = (const char*)(Bw + (size_t)n0 * K);
  char* AsB = (char*)&As[0][0][0];
  char* BsB = (char*)&Bs[0][0][0];
  const size_t rowpitch = (size_t)K * 2;
  const int r0o = row0 * 64 + colb;
  const int r1o = (row0 + 64) * 64 + colb;
  const size_t g0 = (size_t)row0 * rowpitch + colb;
  const size_t g1 = (size_t)(row0 + 64) * rowpitch + colb;

  // preload buffer 0
  async_copy16(Abase + g0, AsB + r0o);
  async_copy16(Abase + g1, AsB + r1o);
  async_copy16(Bbase + g0, BsB + r0o);
  async_copy16(Bbase + g1, BsB + r1o);
  __syncthreads();

  int p = 0;
  for (int kb = 0; kb < K; kb += BK, p ^= 1) {
    // prefetch next K-tile into the other buffer (async, not waited here)
    if (kb + BK < K) {
      size_t ko = (size_t)(kb + BK) * 2;
      int bo = (p ^ 1) * (BM * BK * 2);
      async_copy16(Abase + g0 + ko, AsB + bo + r0o);
      async_copy16(Abase + g1 + ko, AsB + bo + r1o);
      async_copy16(Bbase + g0 + ko, BsB + bo + r0o);
      async_copy16(Bbase + g1 + ko, BsB + bo + r1o);
    }

    bf16x8 afrag[4], bfrag[4];
#pragma unroll
    for (int i = 0; i < 4; ++i) {
      afrag[i] = *(const bf16x8*)&As[p][wm * 64 + i * 16 + l15][quad * 8];
      bfrag[i] = *(const bf16x8*)&Bs[p][wn * 64 + i * 16 + l15][quad * 8];
    }
#pragma unroll
    for (int i = 0; i < 4; ++i)
#pragma unroll
      for (int jj = 0; jj < 4; ++jj)
        acc[i][jj] = __builtin_amdgcn_mfma_f32_16x16x32_bf16(afrag[i], bfrag[jj], acc[i][jj], 0, 0, 0);

    __syncthreads();   // drains prefetch residual + lds reads; one barrier/iter
  }

#pragma unroll
  for (int i = 0; i < 4; ++i) {
#pragma unroll
    for (int jj = 0; jj < 4; ++jj) {
      int row = m0 + wm * 64 + i * 16 + quad * 4;
      int col = n0 + wn * 64 + jj * 16 + l15;
      float* Cp = C + (size_t)row * N + col;
#pragma unroll
      for (int r = 0; r < 4; ++r)
        Cp[(size_t)r * N] = acc[i][jj][r];
    }
  }
}

// ---------------------------------------------------------------------------
// Output-projection GEMM: same XCD swizzle + double-buffer structure.
// ---------------------------------------------------------------------------
__global__ __launch_bounds__(256)
void gemm_bt(const bf16_t* __restrict__ A, const bf16_t* __restrict__ Bw,
             float* __restrict__ C) {
  constexpr int BM = 128, BN = 128, BK = 32, K = D_, N = D_;
  __shared__ __align__(16) bf16_t As[2][BM][BK];
  __shared__ __align__(16) bf16_t Bs[2][BN][BK];

  const int flat = blockIdx.x + 8 * blockIdx.y;    // 0..511
  const int xcd  = flat & 7;
  const int j    = flat >> 3;                      // 0..63
  const int mb   = xcd * 8 + (j >> 3);             // 0..63
  const int nb   = j & 7;

  const int tid  = threadIdx.x;
  const int lane = tid & 63;
  const int wave = tid >> 6;
  const int wm   = wave >> 1;
  const int wn   = wave & 1;
  const int l15  = lane & 15;
  const int quad = lane >> 4;

  const int n0 = nb * BN;
  const int m0 = mb * BM;

  floatx4 acc[4][4] = {};

  const int row0 = tid >> 2;
  const int colb = (tid & 3) * 16;

  const char* Abase = (const char*)(A + (size_t)m0 * K);
  const char* Bbase = (const char*)(Bw + (size_t)n0 * K);
  char* AsB = (char*)&As[0][0][0];
  char* BsB = (char*)&Bs[0][0][0];
  const size_t rowpitch = (size_t)K * 2;
  const int r0o = row0 * 64 + colb;
  const int r1o = (row0 + 64) * 64 + colb;
  const size_t g0 = (size_t)row0 * rowpitch + colb;
  const size_t g1 = (size_t)(row0 + 64) * rowpitch + colb;

  async_copy16(Abase + g0, AsB + r0o);
  async_copy16(Abase + g1, AsB + r1o);
  async_copy16(Bbase + g0, BsB + r0o);
  async_copy16(Bbase + g1, BsB + r1o);
  __syncthreads();

  int p = 0;
  for (int kb = 0; kb < K; kb += BK, p ^= 1) {
    if (kb + BK < K) {
      size_t ko = (size_t)(kb + BK) * 2;
      int bo = (p ^ 1) * (BM * BK * 2);
      async_copy16(Abase + g0 + ko, AsB + bo + r0o);
      async_copy16(Abase + g1 + ko, AsB + bo + r1o);
      async_copy16(Bbase + g0 + ko, BsB + bo + r0o);
      async_copy16(Bbase + g1 + ko, BsB + bo + r1o);
    }

    bf16x8 afrag[4], bfrag[4];
#pragma unroll
    for (int i = 0; i < 4; ++i) {
      afrag[i] = *(const bf16x8*)&As[p][wm * 64 + i * 16 + l15][quad * 8];
      bfrag[i] = *(const bf16x8*)&Bs[p][wn * 64 + i * 16 + l15][quad * 8];
    }
#pragma unroll
    for (int i = 0; i < 4; ++i)
#pragma unroll
      for (int jj = 0; jj < 4; ++jj)
        acc[i][jj] = __builtin_amdgcn_mfma_f32_16x16x32_bf16(afrag[i], bfrag[jj], acc[i][jj], 0, 0, 0);

    __syncthreads();
  }

#pragma unroll
  for (int i = 0; i < 4; ++i) {
#pragma unroll
    for (int jj = 0; jj < 4; ++jj) {
      int row = m0 + wm * 64 + i * 16 + quad * 4;
      int col = n0 + wn * 64 + jj * 16 + l15;
      float* Cp = C + (size_t)row * N + col;
#pragma unroll
      for (int r = 0; r < 4; ++r)
        Cp[(size_t)r * N] = acc[i][jj][r];
    }
  }
}

// ---------------------------------------------------------------------------
// Scan pass 1: chunk-local b-scan from -inf. G[bh][chunk][lane].
// ---------------------------------------------------------------------------
__global__ __launch_bounds__(64)
void wkv_pass1(const float* __restrict__ kbuf, const float* __restrict__ time_decay,
               float* __restrict__ G) {
  __shared__ __align__(16) float ks[CL_][64];
  const int blk   = blockIdx.x;
  const int chunk = blk & (CHUNKS_ - 1);
  const int bh    = blk >> 6;
  const int b = bh >> 4, h = bh & 15;
  const int lane = threadIdx.x;
  const int c = h * HD_ + lane;
  const float w = -__expf(time_decay[c]);

  const size_t gbase = ((size_t)b * S_ + (size_t)chunk * CL_) * D_ + h * HD_;
  const char* kg = (const char*)(kbuf + gbase);
  const int rsel = lane >> 4;
  const int csel = (lane & 15) * 16;
#pragma unroll
  for (int i = 0; i < CL_ / 4; ++i) {
    size_t go = (size_t)(i * 4 + rsel) * (D_ * 4) + csel;
    async_copy16(kg + go, (char*)&ks[0][0] + i * 1024 + lane * 16);
  }
  __builtin_amdgcn_s_waitcnt(0);
  __syncthreads();

  float g = -1e38f;
  for (int t = 0; t < CL_; ++t) {
    float kt = ks[t][lane];
    float ww = g + w;
    float d2 = ww - kt;
    float em = __expf(-fabsf(d2));
    float e1b = (d2 >= 0.0f) ? 1.0f : em;
    float e2b = (d2 >= 0.0f) ? em : 1.0f;
    g = fmaxf(ww, kt) + __logf(e1b + e2b + 1e-8f);
  }
  G[(size_t)bh * (CHUNKS_ * 64) + chunk * 64 + lane] = g;
}

// ---------------------------------------------------------------------------
// Scan pass 2: stage G slab, compute incoming b via exact LSE prefix, store
// si_b, then the chunk's affine a-transfer (A = prod e1b, Bv = run from 0).
// ---------------------------------------------------------------------------
__global__ __launch_bounds__(64)
void wkv_pass2(const float* __restrict__ kbuf, const float* __restrict__ vbuf,
               const float* __restrict__ time_decay, const float* __restrict__ G,
               float* __restrict__ si_b, float* __restrict__ cs_A, float* __restrict__ cs_Bv) {
  __shared__ __align__(16) float Gs[CHUNKS_][64];   // 16 KB
  __shared__ __align__(16) float ks[CL_][64];       // 8 KB
  __shared__ __align__(16) float vs[CL_][64];       // 8 KB
  const int blk   = blockIdx.x;
  const int chunk = blk & (CHUNKS_ - 1);
  const int bh    = blk >> 6;
  const int b = bh >> 4, h = bh & 15;
  const int lane = threadIdx.x;
  const int c = h * HD_ + lane;
  const float w  = -__expf(time_decay[c]);
  const float wL = w * (float)CL_;

  const char* gg = (const char*)(G + (size_t)bh * (CHUNKS_ * 64));
#pragma unroll
  for (int i = 0; i < 16; ++i)
    async_copy16(gg + i * 1024 + lane * 16, (char*)&Gs[0][0] + i * 1024 + lane * 16);

  const size_t gbase = ((size_t)b * S_ + (size_t)chunk * CL_) * D_ + h * HD_;
  const char* kg = (const char*)(kbuf + gbase);
  const char* vg = (const char*)(vbuf + gbase);
  const int rsel = lane >> 4;
  const int csel = (lane & 15) * 16;
#pragma unroll
  for (int i = 0; i < CL_ / 4; ++i) {
    size_t go = (size_t)(i * 4 + rsel) * (D_ * 4) + csel;
    async_copy16(kg + go, (char*)&ks[0][0] + i * 1024 + lane * 16);
    async_copy16(vg + go, (char*)&vs[0][0] + i * 1024 + lane * 16);
  }
  __builtin_amdgcn_s_waitcnt(0);
  __syncthreads();

  float bst = -1e38f;
  for (int ch = 0; ch < chunk; ++ch) {
    float g = Gs[ch][lane];
    float b1 = bst + wL;
    float dd = b1 - g;
    float em = __expf(-fabsf(dd));
    bst = fmaxf(b1, g) + __logf(1.0f + em);
  }
  const size_t so = (size_t)bh * (CHUNKS_ * 64) + chunk * 64 + lane;
  si_b[so] = bst;

  float a = 0.0f, Ap = 1.0f;
  for (int t = 0; t < CL_; ++t) {
    float kt = ks[t][lane], vt = vs[t][lane];
    float ww = bst + w;
    float d2 = ww - kt;
    float em = __expf(-fabsf(d2));
    float e1b = (d2 >= 0.0f) ? 1.0f : em;
    float e2b = (d2 >= 0.0f) ? em : 1.0f;
    a  = e1b * a + e2b * vt;
    Ap = Ap * e1b;
    bst = fmaxf(ww, kt) + __logf(e1b + e2b + 1e-8f);
  }
  cs_A [so] = Ap;
  cs_Bv[so] = a;
}

// ---------------------------------------------------------------------------
// Scan pass 3: affine prefix for incoming a, then exact reference steps;
// fuse sigmoid(r)*wkv and GroupNorm partials. LDS reused across phases.
// ---------------------------------------------------------------------------
__global__ __launch_bounds__(64)
void wkv_pass3(const float* __restrict__ rbuf, const float* __restrict__ kbuf,
               const float* __restrict__ vbuf,
               const float* __restrict__ time_decay, const float* __restrict__ time_first,
               const float* __restrict__ si_b,
               const float* __restrict__ cs_A, const float* __restrict__ cs_Bv,
               float* __restrict__ rwkv, float* __restrict__ psum, float* __restrict__ psq) {
  __shared__ __align__(16) char smem[32 * 1024];
  float (*As_)[64] = (float(*)[64])smem;                 // 16 KB
  float (*Bs_)[64] = (float(*)[64])(smem + 16384);       // 16 KB
  const int blk   = blockIdx.x;
  const int chunk = blk & (CHUNKS_ - 1);
  const int bh    = blk >> 6;
  const int b = bh >> 4, h = bh & 15;
  const int lane = threadIdx.x;
  const int c = h * HD_ + lane;
  const float w = -__expf(time_decay[c]);
  const float u = time_first[c];

  const char* ag = (const char*)(cs_A  + (size_t)bh * (CHUNKS_ * 64));
  const char* bg = (const char*)(cs_Bv + (size_t)bh * (CHUNKS_ * 64));
#pragma unroll
  for (int i = 0; i < 16; ++i) {
    async_copy16(ag + i * 1024 + lane * 16, (char*)&As_[0][0] + i * 1024 + lane * 16);
    async_copy16(bg + i * 1024 + lane * 16, (char*)&Bs_[0][0] + i * 1024 + lane * 16);
  }
  const size_t so = (size_t)bh * (CHUNKS_ * 64) + chunk * 64 + lane;
  float bst = si_b[so];
  __builtin_amdgcn_s_waitcnt(0);
  __syncthreads();

  float a = 0.0f;
  for (int ch = 0; ch < chunk; ++ch)
    a = As_[ch][lane] * a + Bs_[ch][lane];
  __syncthreads();   // done with As_/Bs_ before LDS reuse

  float (*rs)[64] = (float(*)[64])smem;
  float (*ks)[64] = (float(*)[64])(smem + 8192);
  float (*vs)[64] = (float(*)[64])(smem + 16384);
  const size_t gbase = ((size_t)b * S_ + (size_t)chunk * CL_) * D_ + h * HD_;
  const char* rg = (const char*)(rbuf + gbase);
  const char* kg = (const char*)(kbuf + gbase);
  const char* vg = (const char*)(vbuf + gbase);
  const int rsel = lane >> 4;
  const int csel = (lane & 15) * 16;
#pragma unroll
  for (int i = 0; i < CL_ / 4; ++i) {
    size_t go = (size_t)(i * 4 + rsel) * (D_ * 4) + csel;
    async_copy16(rg + go, (char*)&rs[0][0] + i * 1024 + lane * 16);
    async_copy16(kg + go, (char*)&ks[0][0] + i * 1024 + lane * 16);
    async_copy16(vg + go, (char*)&vs[0][0] + i * 1024 + lane * 16);
  }
  __builtin_amdgcn_s_waitcnt(0);
  __syncthreads();

  float sum = 0.0f, sq = 0.0f;
  size_t widx = gbase + lane;
  for (int t = 0; t < CL_; ++t) {
    float kt = ks[t][lane], vt = vs[t][lane], rt = rs[t][lane];
    float wk = kt + u;
    float d1 = bst - wk;
    float em1 = __expf(-fabsf(d1));
    float e1 = (d1 >= 0.0f) ? 1.0f : em1;
    float e2 = (d1 >= 0.0f) ? em1 : 1.0f;
    float out = __fdividef(e1 * a + e2 * vt, e1 + e2 + 1e-8f);

    float ww = bst + w;
    float d2 = ww - kt;
    float em2 = __expf(-fabsf(d2));
    float e1b = (d2 >= 0.0f) ? 1.0f : em2;
    float e2b = (d2 >= 0.0f) ? em2 : 1.0f;
    a   = e1b * a + e2b * vt;
    bst = fmaxf(ww, kt) + __logf(e1b + e2b + 1e-8f);

    float sig = __fdividef(1.0f, 1.0f + __expf(-rt));
    float o2 = sig * out;
    rwkv[widx] = o2;
    sum += o2; sq += o2 * o2;
    widx += D_;
  }

#pragma unroll
  for (int off = 32; off > 0; off >>= 1) {
    sum += __shfl_down(sum, off);
    sq  += __shfl_down(sq, off);
  }
  if (lane == 0) {
    psum[bh * CHUNKS_ + chunk] = sum;
    psq [bh * CHUNKS_ + chunk] = sq;
  }
}

// ---------------------------------------------------------------------------
// GroupNorm: stats finalize fused into apply+cast.
// ---------------------------------------------------------------------------
__global__ __launch_bounds__(256)
void norm_cast(const float* __restrict__ rwkv,
               const float* __restrict__ psum, const float* __restrict__ psq,
               const float* __restrict__ gamma, const float* __restrict__ beta,
               bf16_t* __restrict__ normed) {
  __shared__ float smean[4], srstd[4];
  const int tid = threadIdx.x;
  const int lane = tid & 63;
  const int wj = tid >> 6;
  int idx0 = blockIdx.x * 256;
  int d0 = idx0 & (D_ - 1);
  int bb = idx0 / (S_ * D_);
  int bh = bb * H_ + (d0 >> 6) + wj;

  float s = psum[bh * CHUNKS_ + lane];
  float q = psq [bh * CHUNKS_ + lane];
#pragma unroll
  for (int off = 32; off > 0; off >>= 1) {
    s += __shfl_down(s, off);
    q += __shfl_down(q, off);
  }
  if (lane == 0) {
    const float n = (float)(S_ * HD_);
    float mean = s / n;
    float var  = q / n - mean * mean;
    smean[wj] = mean;
    srstd[wj] = rsqrtf(var + 1e-5f);
  }
  __syncthreads();

  int idx = idx0 + tid;
  int d = idx & (D_ - 1);
  float v = (rwkv[idx] - smean[wj]) * srstd[wj] * gamma[d] + beta[d];
  normed[idx] = (bf16_t)v;
}

// ---------------------------------------------------------------------------
extern "C" void kernel_launch(void* const* d_in, const int* in_sizes, int n_in,
                              void* d_out, int out_size, void* d_ws, size_t ws_size,
                              hipStream_t stream) {
  const float* x     = (const float*)d_in[0];
  const float* tmr   = (const float*)d_in[1];
  const float* tmk   = (const float*)d_in[2];
  const float* tmv   = (const float*)d_in[3];
  const float* Wr    = (const float*)d_in[4];
  const float* Wk    = (const float*)d_in[5];
  const float* Wv    = (const float*)d_in[6];
  const float* Wo    = (const float*)d_in[7];
  const float* td    = (const float*)d_in[8];
  const float* tf    = (const float*)d_in[9];
  const float* gamma = (const float*)d_in[10];
  const float* beta  = (const float*)d_in[11];

  char* ws = (char*)d_ws;
  const size_t MB = 1024 * 1024;
  bf16_t* W_bf   = (bf16_t*)(ws + 0 * MB);     // Wr,Wk,Wv,Wo bf16, contiguous
  bf16_t* Wo_bf  = (bf16_t*)(ws + 6 * MB);
  bf16_t* xr     = (bf16_t*)(ws + 8 * MB);     // 16MB each
  bf16_t* xk     = (bf16_t*)(ws + 24 * MB);
  bf16_t* xv     = (bf16_t*)(ws + 40 * MB);
  float*  rbuf   = (float*)(ws + 56 * MB);     // 32MB each
  float*  kbuf   = (float*)(ws + 88 * MB);
  float*  vbuf   = (float*)(ws + 120 * MB);
  float*  G      = (float*)(ws + 24 * MB);     // scan scratch reuses xk region
  float*  cs_A   = (float*)(ws + 25 * MB);
  float*  cs_Bv  = (float*)(ws + 26 * MB);
  float*  si_b   = (float*)(ws + 27 * MB);
  float*  psum   = (float*)(ws + 28 * MB);
  float*  psq    = (float*)(ws + 28 * MB + 64 * 1024);
  bf16_t* normed = xr;                         // xr dead after gemm3

  float* rwkv = (float*)d_out;                 // d_out doubles as fp32 scratch
  float* outp = (float*)d_out;

  pre_kernel<<<(12 * 1024 * 1024) / 256, 256, 0, stream>>>(
      Wr, Wk, Wv, Wo, W_bf, x, tmr, tmk, tmv, xr, xk, xv);

  gemm3<<<dim3(24, 64), 256, 0, stream>>>(xr, xk, xv, W_bf, rbuf, kbuf, vbuf);

  wkv_pass1<<<B_ * H_ * CHUNKS_, 64, 0, stream>>>(kbuf, td, G);
  wkv_pass2<<<B_ * H_ * CHUNKS_, 64, 0, stream>>>(kbuf, vbuf, td, G, si_b, cs_A, cs_Bv);
  wkv_pass3<<<B_ * H_ * CHUNKS_, 64, 0, stream>>>(rbuf, kbuf, vbuf, td, tf,
                                                  si_b, cs_A, cs_Bv, rwkv, psum, psq);

  norm_cast<<<(M_ * D_) / 256, 256, 0, stream>>>(rwkv, psum, psq, gamma, beta, normed);

  gemm_bt<<<dim3(8, 64), 256, 0, stream>>>(normed, Wo_bf, outp);
}

// Round 8
// 306.661 us; speedup vs baseline: 1.1669x; 1.0407x over previous
//
#include <hip/hip_runtime.h>
#include <cstdint>
#include <cstddef>

#define B_  4
#define S_  2048
#define D_  1024
#define H_  16
#define HD_ 64
#define M_  (B_ * S_)   // 8192 rows

#define CHUNKS_ 64      // parallel chunks per (b,h) sequence
#define CL_     32      // chunk length; CHUNKS_*CL_ == S_

typedef __bf16 bf16_t;
typedef bf16_t bf16x8 __attribute__((ext_vector_type(8)));
typedef float  floatx4 __attribute__((ext_vector_type(4)));

// ---------------------------------------------------------------------------
// async 16B global -> LDS copy (gfx950). LDS dest is wave-uniform base +
// lane*16 (m104/m108); all uses below pass lds = base + lane*16 exactly.
// ---------------------------------------------------------------------------
__device__ __forceinline__ void async_copy16(const void* gmem, void* lds) {
  __builtin_amdgcn_global_load_lds(
      (__attribute__((address_space(1))) void*)const_cast<void*>(gmem),
      (__attribute__((address_space(3))) void*)lds,
      16, 0, 0);
}

// ---------------------------------------------------------------------------
// Fused prologue: weight fp32->bf16 cast (4M elems) + token-shift mix (8M).
// ---------------------------------------------------------------------------
__global__ void pre_kernel(const float* __restrict__ w0, const float* __restrict__ w1,
                           const float* __restrict__ w2, const float* __restrict__ w3,
                           bf16_t* __restrict__ wout,
                           const float* __restrict__ x,
                           const float* __restrict__ tmr, const float* __restrict__ tmk,
                           const float* __restrict__ tmv,
                           bf16_t* __restrict__ xr, bf16_t* __restrict__ xk,
                           bf16_t* __restrict__ xv) {
  const int ONE_M = 1 << 20;
  int gid = blockIdx.x * blockDim.x + threadIdx.x;
  if (gid < 4 * ONE_M) {
    const float* src = (gid < ONE_M) ? w0 : (gid < 2 * ONE_M) ? w1 : (gid < 3 * ONE_M) ? w2 : w3;
    wout[gid] = (bf16_t)src[gid & (ONE_M - 1)];
  } else {
    int idx = gid - 4 * ONE_M;                 // 0 .. 8M-1
    int d = idx & (D_ - 1);
    int t = (idx / D_) & (S_ - 1);
    float xc = x[idx];
    float xp = (t == 0) ? 0.0f : x[idx - D_];
    float mr = tmr[d], mk = tmk[d], mv = tmv[d];
    xr[idx] = (bf16_t)(xc * mr + xp * (1.0f - mr));
    xk[idx] = (bf16_t)(xc * mk + xp * (1.0f - mk));
    xv[idx] = (bf16_t)(xc * mv + xp * (1.0f - mv));
  }
}

// ---------------------------------------------------------------------------
// Fused 3-projection GEMM. XCD swizzle (r6) + double-buffered prefetch (r7).
// r8: bf16 output (halves write traffic; scan reads halve too).
// ---------------------------------------------------------------------------
__global__ __launch_bounds__(256)
void gemm3(const bf16_t* __restrict__ xr, const bf16_t* __restrict__ xk,
           const bf16_t* __restrict__ xv, const bf16_t* __restrict__ Wall,
           bf16_t* __restrict__ rbuf, bf16_t* __restrict__ kbuf, bf16_t* __restrict__ vbuf) {
  constexpr int BM = 128, BN = 128, BK = 32, K = D_, N = D_;
  __shared__ __align__(16) bf16_t As[2][BM][BK];   // 2 x 8 KB
  __shared__ __align__(16) bf16_t Bs[2][BN][BK];   // 2 x 8 KB

  const int flat = blockIdx.x + 24 * blockIdx.y;   // 0..1535
  const int xcd  = flat & 7;
  const int j    = flat >> 3;                      // 0..191
  const int pair = xcd * 24 + (j >> 3);            // 0..191
  const int nb   = j & 7;
  const int proj = pair / 64;
  const int mb   = pair % 64;

  const bf16_t* A  = (proj == 0) ? xr : (proj == 1) ? xk : xv;
  const bf16_t* Bw = Wall + (size_t)proj * (1 << 20);
  bf16_t* C       = (proj == 0) ? rbuf : (proj == 1) ? kbuf : vbuf;

  const int tid  = threadIdx.x;
  const int lane = tid & 63;
  const int wave = tid >> 6;
  const int wm   = wave >> 1;
  const int wn   = wave & 1;
  const int l15  = lane & 15;
  const int quad = lane >> 4;

  const int n0 = nb * BN;
  const int m0 = mb * BM;

  floatx4 acc[4][4] = {};

  const int row0 = tid >> 2;
  const int colb = (tid & 3) * 16;

  const char* Abase = (const char*)(A + (size_t)m0 * K);
  const char* Bbase = (const char*)(Bw + (size_t)n0 * K);
  char* AsB = (char*)&As[0][0][0];
  char* BsB = (char*)&Bs[0][0][0];
  const size_t rowpitch = (size_t)K * 2;
  const int r0o = row0 * 64 + colb;
  const int r1o = (row0 + 64) * 64 + colb;
  const size_t g0 = (size_t)row0 * rowpitch + colb;
  const size_t g1 = (size_t)(row0 + 64) * rowpitch + colb;

  async_copy16(Abase + g0, AsB + r0o);
  async_copy16(Abase + g1, AsB + r1o);
  async_copy16(Bbase + g0, BsB + r0o);
  async_copy16(Bbase + g1, BsB + r1o);
  __syncthreads();

  int p = 0;
  for (int kb = 0; kb < K; kb += BK, p ^= 1) {
    if (kb + BK < K) {
      size_t ko = (size_t)(kb + BK) * 2;
      int bo = (p ^ 1) * (BM * BK * 2);
      async_copy16(Abase + g0 + ko, AsB + bo + r0o);
      async_copy16(Abase + g1 + ko, AsB + bo + r1o);
      async_copy16(Bbase + g0 + ko, BsB + bo + r0o);
      async_copy16(Bbase + g1 + ko, BsB + bo + r1o);
    }

    bf16x8 afrag[4], bfrag[4];
#pragma unroll
    for (int i = 0; i < 4; ++i) {
      afrag[i] = *(const bf16x8*)&As[p][wm * 64 + i * 16 + l15][quad * 8];
      bfrag[i] = *(const bf16x8*)&Bs[p][wn * 64 + i * 16 + l15][quad * 8];
    }
#pragma unroll
    for (int i = 0; i < 4; ++i)
#pragma unroll
      for (int jj = 0; jj < 4; ++jj)
        acc[i][jj] = __builtin_amdgcn_mfma_f32_16x16x32_bf16(afrag[i], bfrag[jj], acc[i][jj], 0, 0, 0);

    __syncthreads();
  }

#pragma unroll
  for (int i = 0; i < 4; ++i) {
#pragma unroll
    for (int jj = 0; jj < 4; ++jj) {
      int row = m0 + wm * 64 + i * 16 + quad * 4;
      int col = n0 + wn * 64 + jj * 16 + l15;
      bf16_t* Cp = C + (size_t)row * N + col;
#pragma unroll
      for (int r = 0; r < 4; ++r)
        Cp[(size_t)r * N] = (bf16_t)acc[i][jj][r];
    }
  }
}

// ---------------------------------------------------------------------------
// Output-projection GEMM: XCD swizzle + double-buffer; fp32 out (d_out).
// ---------------------------------------------------------------------------
__global__ __launch_bounds__(256)
void gemm_bt(const bf16_t* __restrict__ A, const bf16_t* __restrict__ Bw,
             float* __restrict__ C) {
  constexpr int BM = 128, BN = 128, BK = 32, K = D_, N = D_;
  __shared__ __align__(16) bf16_t As[2][BM][BK];
  __shared__ __align__(16) bf16_t Bs[2][BN][BK];

  const int flat = blockIdx.x + 8 * blockIdx.y;    // 0..511
  const int xcd  = flat & 7;
  const int j    = flat >> 3;                      // 0..63
  const int mb   = xcd * 8 + (j >> 3);             // 0..63
  const int nb   = j & 7;

  const int tid  = threadIdx.x;
  const int lane = tid & 63;
  const int wave = tid >> 6;
  const int wm   = wave >> 1;
  const int wn   = wave & 1;
  const int l15  = lane & 15;
  const int quad = lane >> 4;

  const int n0 = nb * BN;
  const int m0 = mb * BM;

  floatx4 acc[4][4] = {};

  const int row0 = tid >> 2;
  const int colb = (tid & 3) * 16;

  const char* Abase = (const char*)(A + (size_t)m0 * K);
  const char* Bbase = (const char*)(Bw + (size_t)n0 * K);
  char* AsB = (char*)&As[0][0][0];
  char* BsB = (char*)&Bs[0][0][0];
  const size_t rowpitch = (size_t)K * 2;
  const int r0o = row0 * 64 + colb;
  const int r1o = (row0 + 64) * 64 + colb;
  const size_t g0 = (size_t)row0 * rowpitch + colb;
  const size_t g1 = (size_t)(row0 + 64) * rowpitch + colb;

  async_copy16(Abase + g0, AsB + r0o);
  async_copy16(Abase + g1, AsB + r1o);
  async_copy16(Bbase + g0, BsB + r0o);
  async_copy16(Bbase + g1, BsB + r1o);
  __syncthreads();

  int p = 0;
  for (int kb = 0; kb < K; kb += BK, p ^= 1) {
    if (kb + BK < K) {
      size_t ko = (size_t)(kb + BK) * 2;
      int bo = (p ^ 1) * (BM * BK * 2);
      async_copy16(Abase + g0 + ko, AsB + bo + r0o);
      async_copy16(Abase + g1 + ko, AsB + bo + r1o);
      async_copy16(Bbase + g0 + ko, BsB + bo + r0o);
      async_copy16(Bbase + g1 + ko, BsB + bo + r1o);
    }

    bf16x8 afrag[4], bfrag[4];
#pragma unroll
    for (int i = 0; i < 4; ++i) {
      afrag[i] = *(const bf16x8*)&As[p][wm * 64 + i * 16 + l15][quad * 8];
      bfrag[i] = *(const bf16x8*)&Bs[p][wn * 64 + i * 16 + l15][quad * 8];
    }
#pragma unroll
    for (int i = 0; i < 4; ++i)
#pragma unroll
      for (int jj = 0; jj < 4; ++jj)
        acc[i][jj] = __builtin_amdgcn_mfma_f32_16x16x32_bf16(afrag[i], bfrag[jj], acc[i][jj], 0, 0, 0);

    __syncthreads();
  }

#pragma unroll
  for (int i = 0; i < 4; ++i) {
#pragma unroll
    for (int jj = 0; jj < 4; ++jj) {
      int row = m0 + wm * 64 + i * 16 + quad * 4;
      int col = n0 + wn * 64 + jj * 16 + l15;
      float* Cp = C + (size_t)row * N + col;
#pragma unroll
      for (int r = 0; r < 4; ++r)
        Cp[(size_t)r * N] = acc[i][jj][r];
    }
  }
}

// ---------------------------------------------------------------------------
// bf16 chunk staging: row = 64 bf16 = 128 B; one wave-instr covers 8 rows
// (8 lanes x 16 B per row). 4 instrs stage a CL=32 chunk (4 KB).
// ---------------------------------------------------------------------------
__device__ __forceinline__ void stage_chunk_bf16(const char* gsrc, char* lds, int lane) {
  const int row = lane >> 3;            // 0..7 within group
  const int cb  = (lane & 7) * 16;
#pragma unroll
  for (int i = 0; i < 4; ++i) {
    size_t go = (size_t)(i * 8 + row) * (D_ * 2) + cb;
    async_copy16(gsrc + go, lds + i * 1024 + lane * 16);
  }
}

// ---------------------------------------------------------------------------
// Scan pass 1: chunk-local b-scan from -inf. G[bh][chunk][lane] (fp32).
// ---------------------------------------------------------------------------
__global__ __launch_bounds__(64)
void wkv_pass1(const bf16_t* __restrict__ kbuf, const float* __restrict__ time_decay,
               float* __restrict__ G) {
  __shared__ __align__(16) bf16_t ks[CL_][64];
  const int blk   = blockIdx.x;
  const int chunk = blk & (CHUNKS_ - 1);
  const int bh    = blk >> 6;
  const int b = bh >> 4, h = bh & 15;
  const int lane = threadIdx.x;
  const int c = h * HD_ + lane;
  const float w = -__expf(time_decay[c]);

  const size_t gbase = ((size_t)b * S_ + (size_t)chunk * CL_) * D_ + h * HD_;
  stage_chunk_bf16((const char*)(kbuf + gbase), (char*)&ks[0][0], lane);
  __builtin_amdgcn_s_waitcnt(0);
  __syncthreads();

  float g = -1e38f;
  for (int t = 0; t < CL_; ++t) {
    float kt = (float)ks[t][lane];
    float ww = g + w;
    float d2 = ww - kt;
    float em = __expf(-fabsf(d2));
    float e1b = (d2 >= 0.0f) ? 1.0f : em;
    float e2b = (d2 >= 0.0f) ? em : 1.0f;
    g = fmaxf(ww, kt) + __logf(e1b + e2b + 1e-8f);
  }
  G[(size_t)bh * (CHUNKS_ * 64) + chunk * 64 + lane] = g;
}

// ---------------------------------------------------------------------------
// Scan pass 2: stage G slab, exact LSE prefix for incoming b, store si_b,
// then the chunk's affine a-transfer (A = prod e1b, Bv = run from 0).
// ---------------------------------------------------------------------------
__global__ __launch_bounds__(64)
void wkv_pass2(const bf16_t* __restrict__ kbuf, const bf16_t* __restrict__ vbuf,
               const float* __restrict__ time_decay, const float* __restrict__ G,
               float* __restrict__ si_b, float* __restrict__ cs_A, float* __restrict__ cs_Bv) {
  __shared__ __align__(16) float Gs[CHUNKS_][64];   // 16 KB
  __shared__ __align__(16) bf16_t ks[CL_][64];      // 4 KB
  __shared__ __align__(16) bf16_t vs[CL_][64];      // 4 KB
  const int blk   = blockIdx.x;
  const int chunk = blk & (CHUNKS_ - 1);
  const int bh    = blk >> 6;
  const int b = bh >> 4, h = bh & 15;
  const int lane = threadIdx.x;
  const int c = h * HD_ + lane;
  const float w  = -__expf(time_decay[c]);
  const float wL = w * (float)CL_;

  const char* gg = (const char*)(G + (size_t)bh * (CHUNKS_ * 64));
#pragma unroll
  for (int i = 0; i < 16; ++i)
    async_copy16(gg + i * 1024 + lane * 16, (char*)&Gs[0][0] + i * 1024 + lane * 16);

  const size_t gbase = ((size_t)b * S_ + (size_t)chunk * CL_) * D_ + h * HD_;
  stage_chunk_bf16((const char*)(kbuf + gbase), (char*)&ks[0][0], lane);
  stage_chunk_bf16((const char*)(vbuf + gbase), (char*)&vs[0][0], lane);
  __builtin_amdgcn_s_waitcnt(0);
  __syncthreads();

  float bst = -1e38f;
  for (int ch = 0; ch < chunk; ++ch) {
    float g = Gs[ch][lane];
    float b1 = bst + wL;
    float dd = b1 - g;
    float em = __expf(-fabsf(dd));
    bst = fmaxf(b1, g) + __logf(1.0f + em);
  }
  const size_t so = (size_t)bh * (CHUNKS_ * 64) + chunk * 64 + lane;
  si_b[so] = bst;

  float a = 0.0f, Ap = 1.0f;
  for (int t = 0; t < CL_; ++t) {
    float kt = (float)ks[t][lane], vt = (float)vs[t][lane];
    float ww = bst + w;
    float d2 = ww - kt;
    float em = __expf(-fabsf(d2));
    float e1b = (d2 >= 0.0f) ? 1.0f : em;
    float e2b = (d2 >= 0.0f) ? em : 1.0f;
    a  = e1b * a + e2b * vt;
    Ap = Ap * e1b;
    bst = fmaxf(ww, kt) + __logf(e1b + e2b + 1e-8f);
  }
  cs_A [so] = Ap;
  cs_Bv[so] = a;
}

// ---------------------------------------------------------------------------
// Scan pass 3: affine prefix for incoming a, then exact reference steps;
// fuse sigmoid(r)*wkv and GroupNorm partials. rwkv written bf16.
// ---------------------------------------------------------------------------
__global__ __launch_bounds__(64)
void wkv_pass3(const bf16_t* __restrict__ rbuf, const bf16_t* __restrict__ kbuf,
               const bf16_t* __restrict__ vbuf,
               const float* __restrict__ time_decay, const float* __restrict__ time_first,
               const float* __restrict__ si_b,
               const float* __restrict__ cs_A, const float* __restrict__ cs_Bv,
               bf16_t* __restrict__ rwkv, float* __restrict__ psum, float* __restrict__ psq) {
  __shared__ __align__(16) char smem[32 * 1024];
  float (*As_)[64] = (float(*)[64])smem;                 // 16 KB
  float (*Bs_)[64] = (float(*)[64])(smem + 16384);       // 16 KB
  const int blk   = blockIdx.x;
  const int chunk = blk & (CHUNKS_ - 1);
  const int bh    = blk >> 6;
  const int b = bh >> 4, h = bh & 15;
  const int lane = threadIdx.x;
  const int c = h * HD_ + lane;
  const float w = -__expf(time_decay[c]);
  const float u = time_first[c];

  const char* ag = (const char*)(cs_A  + (size_t)bh * (CHUNKS_ * 64));
  const char* bg = (const char*)(cs_Bv + (size_t)bh * (CHUNKS_ * 64));
#pragma unroll
  for (int i = 0; i < 16; ++i) {
    async_copy16(ag + i * 1024 + lane * 16, (char*)&As_[0][0] + i * 1024 + lane * 16);
    async_copy16(bg + i * 1024 + lane * 16, (char*)&Bs_[0][0] + i * 1024 + lane * 16);
  }
  const size_t so = (size_t)bh * (CHUNKS_ * 64) + chunk * 64 + lane;
  float bst = si_b[so];
  __builtin_amdgcn_s_waitcnt(0);
  __syncthreads();

  float a = 0.0f;
  for (int ch = 0; ch < chunk; ++ch)
    a = As_[ch][lane] * a + Bs_[ch][lane];
  __syncthreads();   // done with As_/Bs_ before LDS reuse

  bf16_t (*rs)[64] = (bf16_t(*)[64])smem;                 // 4 KB each
  bf16_t (*ks)[64] = (bf16_t(*)[64])(smem + 4096);
  bf16_t (*vs)[64] = (bf16_t(*)[64])(smem + 8192);
  const size_t gbase = ((size_t)b * S_ + (size_t)chunk * CL_) * D_ + h * HD_;
  stage_chunk_bf16((const char*)(rbuf + gbase), (char*)&rs[0][0], lane);
  stage_chunk_bf16((const char*)(kbuf + gbase), (char*)&ks[0][0], lane);
  stage_chunk_bf16((const char*)(vbuf + gbase), (char*)&vs[0][0], lane);
  __builtin_amdgcn_s_waitcnt(0);
  __syncthreads();

  float sum = 0.0f, sq = 0.0f;
  size_t widx = gbase + lane;
  for (int t = 0; t < CL_; ++t) {
    float kt = (float)ks[t][lane], vt = (float)vs[t][lane], rt = (float)rs[t][lane];
    float wk = kt + u;
    float d1 = bst - wk;
    float em1 = __expf(-fabsf(d1));
    float e1 = (d1 >= 0.0f) ? 1.0f : em1;
    float e2 = (d1 >= 0.0f) ? em1 : 1.0f;
    float out = __fdividef(e1 * a + e2 * vt, e1 + e2 + 1e-8f);

    float ww = bst + w;
    float d2 = ww - kt;
    float em2 = __expf(-fabsf(d2));
    float e1b = (d2 >= 0.0f) ? 1.0f : em2;
    float e2b = (d2 >= 0.0f) ? em2 : 1.0f;
    a   = e1b * a + e2b * vt;
    bst = fmaxf(ww, kt) + __logf(e1b + e2b + 1e-8f);

    float sig = __fdividef(1.0f, 1.0f + __expf(-rt));
    float o2 = sig * out;
    rwkv[widx] = (bf16_t)o2;
    sum += o2; sq += o2 * o2;
    widx += D_;
  }

#pragma unroll
  for (int off = 32; off > 0; off >>= 1) {
    sum += __shfl_down(sum, off);
    sq  += __shfl_down(sq, off);
  }
  if (lane == 0) {
    psum[bh * CHUNKS_ + chunk] = sum;
    psq [bh * CHUNKS_ + chunk] = sq;
  }
}

// ---------------------------------------------------------------------------
// GroupNorm: stats finalize fused into apply+cast. bf16 in/out.
// ---------------------------------------------------------------------------
__global__ __launch_bounds__(256)
void norm_cast(const bf16_t* __restrict__ rwkv,
               const float* __restrict__ psum, const float* __restrict__ psq,
               const float* __restrict__ gamma, const float* __restrict__ beta,
               bf16_t* __restrict__ normed) {
  __shared__ float smean[4], srstd[4];
  const int tid = threadIdx.x;
  const int lane = tid & 63;
  const int wj = tid >> 6;
  int idx0 = blockIdx.x * 256;
  int d0 = idx0 & (D_ - 1);
  int bb = idx0 / (S_ * D_);
  int bh = bb * H_ + (d0 >> 6) + wj;

  float s = psum[bh * CHUNKS_ + lane];
  float q = psq [bh * CHUNKS_ + lane];
#pragma unroll
  for (int off = 32; off > 0; off >>= 1) {
    s += __shfl_down(s, off);
    q += __shfl_down(q, off);
  }
  if (lane == 0) {
    const float n = (float)(S_ * HD_);
    float mean = s / n;
    float var  = q / n - mean * mean;
    smean[wj] = mean;
    srstd[wj] = rsqrtf(var + 1e-5f);
  }
  __syncthreads();

  int idx = idx0 + tid;
  int d = idx & (D_ - 1);
  float v = ((float)rwkv[idx] - smean[wj]) * srstd[wj] * gamma[d] + beta[d];
  normed[idx] = (bf16_t)v;
}

// ---------------------------------------------------------------------------
extern "C" void kernel_launch(void* const* d_in, const int* in_sizes, int n_in,
                              void* d_out, int out_size, void* d_ws, size_t ws_size,
                              hipStream_t stream) {
  const float* x     = (const float*)d_in[0];
  const float* tmr   = (const float*)d_in[1];
  const float* tmk   = (const float*)d_in[2];
  const float* tmv   = (const float*)d_in[3];
  const float* Wr    = (const float*)d_in[4];
  const float* Wk    = (const float*)d_in[5];
  const float* Wv    = (const float*)d_in[6];
  const float* Wo    = (const float*)d_in[7];
  const float* td    = (const float*)d_in[8];
  const float* tf    = (const float*)d_in[9];
  const float* gamma = (const float*)d_in[10];
  const float* beta  = (const float*)d_in[11];

  char* ws = (char*)d_ws;
  const size_t MB = 1024 * 1024;
  bf16_t* W_bf    = (bf16_t*)(ws + 0 * MB);    // Wr,Wk,Wv,Wo bf16, 8 MB
  bf16_t* Wo_bf   = (bf16_t*)(ws + 6 * MB);
  bf16_t* xr      = (bf16_t*)(ws + 8 * MB);    // 16 MB each
  bf16_t* xk      = (bf16_t*)(ws + 24 * MB);
  bf16_t* xv      = (bf16_t*)(ws + 40 * MB);
  // scan scratch reuses xk/xv region (dead after gemm3)
  float*  G       = (float*)(ws + 24 * MB);    // 1 MB each
  float*  cs_A    = (float*)(ws + 25 * MB);
  float*  cs_Bv   = (float*)(ws + 26 * MB);
  float*  si_b    = (float*)(ws + 27 * MB);
  float*  psum    = (float*)(ws + 28 * MB);    // 16 KB each
  float*  psq     = (float*)(ws + 28 * MB + 64 * 1024);
  bf16_t* rwkv    = (bf16_t*)(ws + 30 * MB);   // 16 MB (in dead xk/xv space)
  bf16_t* rbuf    = (bf16_t*)(ws + 56 * MB);   // 16 MB each, bf16
  bf16_t* kbuf    = (bf16_t*)(ws + 72 * MB);
  bf16_t* vbuf    = (bf16_t*)(ws + 88 * MB);
  bf16_t* normed  = xr;                        // xr dead after gemm3

  float* outp = (float*)d_out;

  pre_kernel<<<(12 * 1024 * 1024) / 256, 256, 0, stream>>>(
      Wr, Wk, Wv, Wo, W_bf, x, tmr, tmk, tmv, xr, xk, xv);

  gemm3<<<dim3(24, 64), 256, 0, stream>>>(xr, xk, xv, W_bf, rbuf, kbuf, vbuf);

  wkv_pass1<<<B_ * H_ * CHUNKS_, 64, 0, stream>>>(kbuf, td, G);
  wkv_pass2<<<B_ * H_ * CHUNKS_, 64, 0, stream>>>(kbuf, vbuf, td, G, si_b, cs_A, cs_Bv);
  wkv_pass3<<<B_ * H_ * CHUNKS_, 64, 0, stream>>>(rbuf, kbuf, vbuf, td, tf,
                                                  si_b, cs_A, cs_Bv, rwkv, psum, psq);

  norm_cast<<<(M_ * D_) / 256, 256, 0, stream>>>(rwkv, psum, psq, gamma, beta, normed);

  gemm_bt<<<dim3(8, 64), 256, 0, stream>>>(normed, Wo_bf, outp);
}